// Round 3
// baseline (721.618 us; speedup 1.0000x reference)
//
#include <hip/hip_runtime.h>

// GCN decoder: 2x GCNConv (self-loops, symmetric norm) + FC to 1024.
// n = 50000 nodes, E = 800000 directed edges, feats 64 -> 64 -> 32 -> 1024.
// Round 3: FC register-blocked (2 cols/thread in VGPRs, 128-row X strip in LDS).

#define TB 256
#define FC_ROWS 128

// ---- CSR build ----------------------------------------------------------

__global__ void k_hist(const int* __restrict__ dst, int* __restrict__ cnt, int E) {
    int e = blockIdx.x * TB + threadIdx.x;
    if (e < E) atomicAdd(&cnt[dst[e]], 1);
}

__global__ void k_dinv(const int* __restrict__ cnt, float* __restrict__ dinv, int n) {
    int i = blockIdx.x * TB + threadIdx.x;
    if (i < n) dinv[i] = rsqrtf((float)(cnt[i] + 1));  // +1 self-loop
}

// Exclusive scan of cnt[0..n) -> off[0..n], single block of 1024 threads.
__global__ void k_scan(const int* __restrict__ cnt, int* __restrict__ off, int n) {
    __shared__ int wsum[16];
    __shared__ int carry_s;
    int lane = threadIdx.x & 63;
    int wid = threadIdx.x >> 6;
    if (threadIdx.x == 0) carry_s = 0;
    __syncthreads();
    for (int base = 0; base < n; base += 1024) {
        int i = base + threadIdx.x;
        int v = (i < n) ? cnt[i] : 0;
        int x = v;  // inclusive wave scan
#pragma unroll
        for (int ofs = 1; ofs < 64; ofs <<= 1) {
            int t = __shfl_up(x, ofs, 64);
            if (lane >= ofs) x += t;
        }
        if (lane == 63) wsum[wid] = x;
        __syncthreads();
        int wprefix = 0;
        for (int wv = 0; wv < wid; ++wv) wprefix += wsum[wv];
        int carry = carry_s;
        if (i < n) off[i] = carry + wprefix + x - v;
        __syncthreads();
        if (threadIdx.x == 0) {
            int tot = 0;
            for (int wv = 0; wv < 16; ++wv) tot += wsum[wv];
            carry_s += tot;
        }
        __syncthreads();
    }
    if (threadIdx.x == 0) off[n] = carry_s;
}

__global__ void k_fill(const int* __restrict__ src, const int* __restrict__ dst,
                       const int* __restrict__ off, int* __restrict__ cursor,
                       int* __restrict__ eSrc, int E) {
    int e = blockIdx.x * TB + threadIdx.x;
    if (e >= E) return;
    int d = dst[e];
    int pos = off[d] + atomicAdd(&cursor[d], 1);
    eSrc[pos] = src[e];
}

// ---- dense GEMMs --------------------------------------------------------

// Y[n,64] = X[n,64] @ W[64,64]; W staged in LDS; 4 rows per 256-thread block.
__global__ void k_gemm_x64(const float* __restrict__ X, const float* __restrict__ W,
                           float* __restrict__ Y, int n) {
    __shared__ float Ws[64 * 64];
    for (int i = threadIdx.x; i < 64 * 64; i += TB) Ws[i] = W[i];
    __syncthreads();
    int c = threadIdx.x & 63;
    int r = blockIdx.x * 4 + (threadIdx.x >> 6);
    if (r >= n) return;
    const float* x = X + (size_t)r * 64;
    float acc = 0.f;
#pragma unroll
    for (int k = 0; k < 64; ++k) acc = fmaf(x[k], Ws[k * 64 + c], acc);
    Y[(size_t)r * 64 + c] = acc;
}

// Y[n,32] = X[n,64] @ W[64,32]; 8 rows per block.
__global__ void k_gemm_64_32(const float* __restrict__ X, const float* __restrict__ W,
                             float* __restrict__ Y, int n) {
    __shared__ float Ws[64 * 32];
    for (int i = threadIdx.x; i < 64 * 32; i += TB) Ws[i] = W[i];
    __syncthreads();
    int c = threadIdx.x & 31;
    int r = blockIdx.x * 8 + (threadIdx.x >> 5);
    if (r >= n) return;
    const float* x = X + (size_t)r * 64;
    float acc = 0.f;
#pragma unroll
    for (int k = 0; k < 64; ++k) acc = fmaf(x[k], Ws[k * 32 + c], acc);
    Y[(size_t)r * 32 + c] = acc;
}

// ---- gather-based aggregation (fused norm + self-loop + bias [+relu]) ----

__global__ void k_agg64(const float* __restrict__ H, const int* __restrict__ off,
                        const int* __restrict__ eSrc, const float* __restrict__ dinv,
                        const float* __restrict__ b, float* __restrict__ out, int n) {
    int node = blockIdx.x * 4 + (threadIdx.x >> 6);
    if (node >= n) return;
    int lane = threadIdx.x & 63;
    int j0 = off[node], j1 = off[node + 1];
    float acc = 0.f;
    for (int j = j0; j < j1; ++j) {
        int s = eSrc[j];
        acc = fmaf(dinv[s], H[(size_t)s * 64 + lane], acc);
    }
    float dv = dinv[node];
    float v = fmaf(acc + H[(size_t)node * 64 + lane] * dv, dv, b[lane]);
    out[(size_t)node * 64 + lane] = fmaxf(v, 0.f);
}

__global__ void k_agg32(const float* __restrict__ H, const int* __restrict__ off,
                        const int* __restrict__ eSrc, const float* __restrict__ dinv,
                        const float* __restrict__ b, float* __restrict__ out, int n) {
    int node = blockIdx.x * 8 + (threadIdx.x >> 5);
    if (node >= n) return;
    int lane = threadIdx.x & 31;
    int j0 = off[node], j1 = off[node + 1];
    float acc = 0.f;
    for (int j = j0; j < j1; ++j) {
        int s = eSrc[j];
        acc = fmaf(dinv[s], H[(size_t)s * 32 + lane], acc);
    }
    float dv = dinv[node];
    out[(size_t)node * 32 + lane] = fmaf(acc + H[(size_t)node * 32 + lane] * dv, dv, b[lane]);
}

// ---- FC: Y[n,1024] = X[n,32] @ W[32,1024] + bias ------------------------
// grid = (2 col-halves, row strips). Each thread owns 2 W columns (c, c+256)
// in 64 VGPRs; X strip staged in LDS; inner loop pure register fma.
__global__ void k_fc2(const float* __restrict__ X, const float* __restrict__ W,
                      const float* __restrict__ bias, float* __restrict__ Y, int n) {
    __shared__ float Xs[FC_ROWS * 32];
    int c0 = blockIdx.x * 512 + threadIdx.x;  // second column = c0 + 256
    int r0 = blockIdx.y * FC_ROWS;
    int rows = min(FC_ROWS, n - r0);

    float w0[32], w1[32];
#pragma unroll
    for (int k = 0; k < 32; ++k) {
        w0[k] = W[k * 1024 + c0];
        w1[k] = W[k * 1024 + c0 + 256];
    }
    float b0 = bias[c0], b1 = bias[c0 + 256];

    // stage X strip (rows*32 floats) as float4
    {
        const float4* Xg = (const float4*)(X + (size_t)r0 * 32);
        float4* Xs4 = (float4*)Xs;
        int tot4 = rows * 8;
        for (int i = threadIdx.x; i < tot4; i += TB) Xs4[i] = Xg[i];
    }
    __syncthreads();

    for (int r = 0; r < rows; ++r) {
        const float* x = Xs + r * 32;
        float a0 = b0, a1 = b1;
#pragma unroll
        for (int k = 0; k < 32; ++k) {
            float xv = x[k];
            a0 = fmaf(xv, w0[k], a0);
            a1 = fmaf(xv, w1[k], a1);
        }
        size_t o = (size_t)(r0 + r) * 1024;
        Y[o + c0] = a0;
        Y[o + c0 + 256] = a1;
    }
}

// ---- launch -------------------------------------------------------------

extern "C" void kernel_launch(void* const* d_in, const int* in_sizes, int n_in,
                              void* d_out, int out_size, void* d_ws, size_t ws_size,
                              hipStream_t stream) {
    const float* z   = (const float*)d_in[0];
    const int*   ei  = (const int*)d_in[1];
    const float* W1  = (const float*)d_in[2];
    const float* b1  = (const float*)d_in[3];
    const float* W2  = (const float*)d_in[4];
    const float* b2  = (const float*)d_in[5];
    const float* Wfc = (const float*)d_in[6];
    const float* bfc = (const float*)d_in[7];
    float* out = (float*)d_out;

    int n = in_sizes[0] / 64;
    int E = in_sizes[1] / 2;
    const int* src = ei;
    const int* dst = ei + E;

    // Workspace layout (4-byte words):
    //   cnt[n] | cursor[n] | off[n+1] | eSrc[E] | dinv[n] | bufA[n*64] | bufB[n*64]
    int* cnt    = (int*)d_ws;
    int* cursor = cnt + n;
    int* off    = cursor + n;
    int* eSrc   = off + (n + 1);
    float* dinv = (float*)(eSrc + E);
    float* bufA = dinv + n;
    float* bufB = bufA + (size_t)n * 64;
    float* h2   = bufA;
    float* agg2 = bufA + (size_t)n * 32;

    // ---- CSR build + norms ----
    hipMemsetAsync(cnt, 0, (size_t)2 * n * sizeof(int), stream);  // cnt + cursor
    k_hist<<<(E + TB - 1) / TB, TB, 0, stream>>>(dst, cnt, E);
    k_dinv<<<(n + TB - 1) / TB, TB, 0, stream>>>(cnt, dinv, n);
    k_scan<<<1, 1024, 0, stream>>>(cnt, off, n);
    k_fill<<<(E + TB - 1) / TB, TB, 0, stream>>>(src, dst, off, cursor, eSrc, E);

    // ---- conv1: h1 = z @ W1 ; gather-agg (+b1, relu) -> bufB ----
    k_gemm_x64<<<(n + 3) / 4, TB, 0, stream>>>(z, W1, bufA, n);
    k_agg64<<<(n + 3) / 4, TB, 0, stream>>>(bufA, off, eSrc, dinv, b1, bufB, n);

    // ---- conv2: h2 = bufB @ W2 ; gather-agg (+b2) -> agg2 ----
    k_gemm_64_32<<<(n + 7) / 8, TB, 0, stream>>>(bufB, W2, h2, n);
    k_agg32<<<(n + 7) / 8, TB, 0, stream>>>(h2, off, eSrc, dinv, b2, agg2, n);

    // ---- fc: out = agg2 @ Wfc + bfc ----
    {
        dim3 grid(2, (n + FC_ROWS - 1) / FC_ROWS);
        k_fc2<<<grid, TB, 0, stream>>>(agg2, Wfc, bfc, out, n);
    }
}

// Round 4
// 324.328 us; speedup vs baseline: 2.2250x; 2.2250x over previous
//
#include <hip/hip_runtime.h>

// GCN decoder: 2x GCNConv (self-loops, symmetric norm) + FC to 1024.
// n = 50000 nodes, E = 800000 directed edges, feats 64 -> 64 -> 32 -> 1024.
// Round 4: FC with __launch_bounds__ (real register blocking, nt stores);
//          dinv folded into GEMM epilogue; agg loops 4-way unrolled.

#define TB 256
#define FC_ROWS 64

// ---- CSR build ----------------------------------------------------------

__global__ void k_hist(const int* __restrict__ dst, int* __restrict__ cnt, int E) {
    int e = blockIdx.x * TB + threadIdx.x;
    if (e < E) atomicAdd(&cnt[dst[e]], 1);
}

__global__ void k_dinv(const int* __restrict__ cnt, float* __restrict__ dinv, int n) {
    int i = blockIdx.x * TB + threadIdx.x;
    if (i < n) dinv[i] = rsqrtf((float)(cnt[i] + 1));  // +1 self-loop
}

// Exclusive scan of cnt[0..n) -> off[0..n], single block of 1024 threads.
__global__ void k_scan(const int* __restrict__ cnt, int* __restrict__ off, int n) {
    __shared__ int wsum[16];
    __shared__ int carry_s;
    int lane = threadIdx.x & 63;
    int wid = threadIdx.x >> 6;
    if (threadIdx.x == 0) carry_s = 0;
    __syncthreads();
    for (int base = 0; base < n; base += 1024) {
        int i = base + threadIdx.x;
        int v = (i < n) ? cnt[i] : 0;
        int x = v;  // inclusive wave scan
#pragma unroll
        for (int ofs = 1; ofs < 64; ofs <<= 1) {
            int t = __shfl_up(x, ofs, 64);
            if (lane >= ofs) x += t;
        }
        if (lane == 63) wsum[wid] = x;
        __syncthreads();
        int wprefix = 0;
        for (int wv = 0; wv < wid; ++wv) wprefix += wsum[wv];
        int carry = carry_s;
        if (i < n) off[i] = carry + wprefix + x - v;
        __syncthreads();
        if (threadIdx.x == 0) {
            int tot = 0;
            for (int wv = 0; wv < 16; ++wv) tot += wsum[wv];
            carry_s += tot;
        }
        __syncthreads();
    }
    if (threadIdx.x == 0) off[n] = carry_s;
}

__global__ void k_fill(const int* __restrict__ src, const int* __restrict__ dst,
                       const int* __restrict__ off, int* __restrict__ cursor,
                       int* __restrict__ eSrc, int E) {
    int e = blockIdx.x * TB + threadIdx.x;
    if (e >= E) return;
    int d = dst[e];
    int pos = off[d] + atomicAdd(&cursor[d], 1);
    eSrc[pos] = src[e];
}

// ---- dense GEMMs (epilogue scales row by dinv[r]) -----------------------

// Y[r,c] = dinv[r] * sum_k X[r,k] W[k,c];  64x64 W in LDS; 4 rows/block.
__global__ void k_gemm_x64(const float* __restrict__ X, const float* __restrict__ W,
                           const float* __restrict__ dinv, float* __restrict__ Y, int n) {
    __shared__ float Ws[64 * 64];
    for (int i = threadIdx.x; i < 64 * 64; i += TB) Ws[i] = W[i];
    __syncthreads();
    int c = threadIdx.x & 63;
    int r = blockIdx.x * 4 + (threadIdx.x >> 6);
    if (r >= n) return;
    const float* x = X + (size_t)r * 64;
    float acc = 0.f;
#pragma unroll
    for (int k = 0; k < 64; ++k) acc = fmaf(x[k], Ws[k * 64 + c], acc);
    Y[(size_t)r * 64 + c] = acc * dinv[r];
}

// Y[r,c] = dinv[r] * sum_k X[r,k] W[k,c];  64x32 W in LDS; 8 rows/block.
__global__ void k_gemm_64_32(const float* __restrict__ X, const float* __restrict__ W,
                             const float* __restrict__ dinv, float* __restrict__ Y, int n) {
    __shared__ float Ws[64 * 32];
    for (int i = threadIdx.x; i < 64 * 32; i += TB) Ws[i] = W[i];
    __syncthreads();
    int c = threadIdx.x & 31;
    int r = blockIdx.x * 8 + (threadIdx.x >> 5);
    if (r >= n) return;
    const float* x = X + (size_t)r * 64;
    float acc = 0.f;
#pragma unroll
    for (int k = 0; k < 64; ++k) acc = fmaf(x[k], Ws[k * 32 + c], acc);
    Y[(size_t)r * 32 + c] = acc * dinv[r];
}

// ---- gather aggregation on pre-scaled H' (= dinv .* H) -------------------
// out[i,c] = relu?( (sum_{s in N(i)} H'[s,c] + H'[i,c]) * dinv[i] + b[c] )

__global__ void k_agg64(const float* __restrict__ H, const int* __restrict__ off,
                        const int* __restrict__ eSrc, const float* __restrict__ dinv,
                        const float* __restrict__ b, float* __restrict__ out, int n) {
    int node = blockIdx.x * 4 + (threadIdx.x >> 6);
    if (node >= n) return;
    int lane = threadIdx.x & 63;
    int j0 = off[node], j1 = off[node + 1];
    float a0 = 0.f, a1 = 0.f, a2 = 0.f, a3 = 0.f;
    int j = j0;
    for (; j + 4 <= j1; j += 4) {
        int s0 = eSrc[j], s1 = eSrc[j + 1], s2 = eSrc[j + 2], s3 = eSrc[j + 3];
        a0 += H[(size_t)s0 * 64 + lane];
        a1 += H[(size_t)s1 * 64 + lane];
        a2 += H[(size_t)s2 * 64 + lane];
        a3 += H[(size_t)s3 * 64 + lane];
    }
    for (; j < j1; ++j) a0 += H[(size_t)eSrc[j] * 64 + lane];
    float acc = (a0 + a1) + (a2 + a3) + H[(size_t)node * 64 + lane];
    float v = fmaf(acc, dinv[node], b[lane]);
    out[(size_t)node * 64 + lane] = fmaxf(v, 0.f);
}

__global__ void k_agg32(const float* __restrict__ H, const int* __restrict__ off,
                        const int* __restrict__ eSrc, const float* __restrict__ dinv,
                        const float* __restrict__ b, float* __restrict__ out, int n) {
    int node = blockIdx.x * 8 + (threadIdx.x >> 5);
    if (node >= n) return;
    int lane = threadIdx.x & 31;
    int j0 = off[node], j1 = off[node + 1];
    float a0 = 0.f, a1 = 0.f, a2 = 0.f, a3 = 0.f;
    int j = j0;
    for (; j + 4 <= j1; j += 4) {
        int s0 = eSrc[j], s1 = eSrc[j + 1], s2 = eSrc[j + 2], s3 = eSrc[j + 3];
        a0 += H[(size_t)s0 * 32 + lane];
        a1 += H[(size_t)s1 * 32 + lane];
        a2 += H[(size_t)s2 * 32 + lane];
        a3 += H[(size_t)s3 * 32 + lane];
    }
    for (; j < j1; ++j) a0 += H[(size_t)eSrc[j] * 32 + lane];
    float acc = (a0 + a1) + (a2 + a3) + H[(size_t)node * 32 + lane];
    out[(size_t)node * 32 + lane] = fmaf(acc, dinv[node], b[lane]);
}

// ---- FC: Y[n,1024] = X[n,32] @ W[32,1024] + bias ------------------------
// Each thread owns 2 W columns (c0, c0+256) in 64 VGPRs (launch_bounds caps
// at 128 VGPR so they actually live in registers); X strip in LDS; nt stores.
__global__ __launch_bounds__(TB, 4)
void k_fc2(const float* __restrict__ X, const float* __restrict__ W,
           const float* __restrict__ bias, float* __restrict__ Y, int n) {
    __shared__ float Xs[FC_ROWS * 32];
    int c0 = blockIdx.x * 512 + threadIdx.x;  // second column = c0 + 256
    int r0 = blockIdx.y * FC_ROWS;
    int rows = min(FC_ROWS, n - r0);

    float w0[32], w1[32];
#pragma unroll
    for (int k = 0; k < 32; ++k) {
        w0[k] = W[k * 1024 + c0];
        w1[k] = W[k * 1024 + c0 + 256];
    }
    float b0 = bias[c0], b1 = bias[c0 + 256];

    {
        const float4* Xg = (const float4*)(X + (size_t)r0 * 32);
        float4* Xs4 = (float4*)Xs;
        int tot4 = rows * 8;
        for (int i = threadIdx.x; i < tot4; i += TB) Xs4[i] = Xg[i];
    }
    __syncthreads();

    for (int r = 0; r < rows; ++r) {
        const float* x = Xs + r * 32;
        float a0 = b0, a1 = b1;
#pragma unroll
        for (int k = 0; k < 32; ++k) {
            float xv = x[k];
            a0 = fmaf(xv, w0[k], a0);
            a1 = fmaf(xv, w1[k], a1);
        }
        size_t o = (size_t)(r0 + r) * 1024;
        __builtin_nontemporal_store(a0, &Y[o + c0]);
        __builtin_nontemporal_store(a1, &Y[o + c0 + 256]);
    }
}

// ---- launch -------------------------------------------------------------

extern "C" void kernel_launch(void* const* d_in, const int* in_sizes, int n_in,
                              void* d_out, int out_size, void* d_ws, size_t ws_size,
                              hipStream_t stream) {
    const float* z   = (const float*)d_in[0];
    const int*   ei  = (const int*)d_in[1];
    const float* W1  = (const float*)d_in[2];
    const float* b1  = (const float*)d_in[3];
    const float* W2  = (const float*)d_in[4];
    const float* b2  = (const float*)d_in[5];
    const float* Wfc = (const float*)d_in[6];
    const float* bfc = (const float*)d_in[7];
    float* out = (float*)d_out;

    int n = in_sizes[0] / 64;
    int E = in_sizes[1] / 2;
    const int* src = ei;
    const int* dst = ei + E;

    // Workspace layout (4-byte words):
    //   cnt[n] | cursor[n] | off[n+1] | eSrc[E] | dinv[n] | bufA[n*64] | bufB[n*64]
    int* cnt    = (int*)d_ws;
    int* cursor = cnt + n;
    int* off    = cursor + n;
    int* eSrc   = off + (n + 1);
    float* dinv = (float*)(eSrc + E);
    float* bufA = dinv + n;
    float* bufB = bufA + (size_t)n * 64;
    float* h2   = bufA;
    float* agg2 = bufA + (size_t)n * 32;

    // ---- CSR build + norms ----
    hipMemsetAsync(cnt, 0, (size_t)2 * n * sizeof(int), stream);  // cnt + cursor
    k_hist<<<(E + TB - 1) / TB, TB, 0, stream>>>(dst, cnt, E);
    k_dinv<<<(n + TB - 1) / TB, TB, 0, stream>>>(cnt, dinv, n);
    k_scan<<<1, 1024, 0, stream>>>(cnt, off, n);
    k_fill<<<(E + TB - 1) / TB, TB, 0, stream>>>(src, dst, off, cursor, eSrc, E);

    // ---- conv1: h1' = dinv .* (z @ W1) ; gather-agg (+b1, relu) -> bufB ----
    k_gemm_x64<<<(n + 3) / 4, TB, 0, stream>>>(z, W1, dinv, bufA, n);
    k_agg64<<<(n + 3) / 4, TB, 0, stream>>>(bufA, off, eSrc, dinv, b1, bufB, n);

    // ---- conv2: h2' = dinv .* (bufB @ W2) ; gather-agg (+b2) -> agg2 ----
    k_gemm_64_32<<<(n + 7) / 8, TB, 0, stream>>>(bufB, W2, dinv, h2, n);
    k_agg32<<<(n + 7) / 8, TB, 0, stream>>>(h2, off, eSrc, dinv, b2, agg2, n);

    // ---- fc: out = agg2 @ Wfc + bfc ----
    {
        dim3 grid(2, (n + FC_ROWS - 1) / FC_ROWS);
        k_fc2<<<grid, TB, 0, stream>>>(agg2, Wfc, bfc, out, n);
    }
}

// Round 5
// 287.433 us; speedup vs baseline: 2.5106x; 1.1284x over previous
//
#include <hip/hip_runtime.h>

// GCN decoder: 2x GCNConv (self-loops, symmetric norm) + FC to 1024.
// n = 50000 nodes, E = 800000 directed edges, feats 64 -> 64 -> 32 -> 1024.
// Round 5: own zero-kernel (hipMemsetAsync's fill node cost ~120us/replay!);
//          int4-wide scan; agg kernels use slot-parallel float4 gathers.

#define TB 256
#define FC_ROWS 64

// ---- utility ------------------------------------------------------------

__global__ void k_zero(int4* __restrict__ p, int n4) {
    int i = blockIdx.x * TB + threadIdx.x;
    if (i < n4) p[i] = make_int4(0, 0, 0, 0);
}

// ---- CSR build ----------------------------------------------------------

__global__ void k_hist(const int* __restrict__ dst, int* __restrict__ cnt, int E) {
    int e = blockIdx.x * TB + threadIdx.x;
    if (e < E) atomicAdd(&cnt[dst[e]], 1);
}

__global__ void k_dinv(const int* __restrict__ cnt, float* __restrict__ dinv, int n) {
    int i = blockIdx.x * TB + threadIdx.x;
    if (i < n) dinv[i] = rsqrtf((float)(cnt[i] + 1));  // +1 self-loop
}

// Exclusive scan of cnt[0..n) -> off[0..n]; single block, 4 elems/thread.
__global__ void k_scan(const int* __restrict__ cnt, int* __restrict__ off, int n) {
    __shared__ int wsum[16];
    __shared__ int carry_s;
    int lane = threadIdx.x & 63;
    int wid = threadIdx.x >> 6;
    if (threadIdx.x == 0) carry_s = 0;
    __syncthreads();
    for (int base = 0; base < n; base += 4096) {
        int i4 = base + threadIdx.x * 4;
        int v0 = 0, v1 = 0, v2 = 0, v3 = 0;
        if (i4 + 3 < n) {
            int4 t = *(const int4*)(cnt + i4);
            v0 = t.x; v1 = t.y; v2 = t.z; v3 = t.w;
        } else {
            if (i4 < n) v0 = cnt[i4];
            if (i4 + 1 < n) v1 = cnt[i4 + 1];
            if (i4 + 2 < n) v2 = cnt[i4 + 2];
            if (i4 + 3 < n) v3 = cnt[i4 + 3];
        }
        int s = v0 + v1 + v2 + v3;
        int x = s;  // inclusive wave scan of per-thread sums
#pragma unroll
        for (int ofs = 1; ofs < 64; ofs <<= 1) {
            int t = __shfl_up(x, ofs, 64);
            if (lane >= ofs) x += t;
        }
        if (lane == 63) wsum[wid] = x;
        __syncthreads();
        int wprefix = 0;
        for (int wv = 0; wv < 16; ++wv) wprefix += (wv < wid) ? wsum[wv] : 0;
        int excl = carry_s + wprefix + x - s;
        if (i4 < n) off[i4] = excl;
        if (i4 + 1 < n) off[i4 + 1] = excl + v0;
        if (i4 + 2 < n) off[i4 + 2] = excl + v0 + v1;
        if (i4 + 3 < n) off[i4 + 3] = excl + v0 + v1 + v2;
        __syncthreads();
        if (threadIdx.x == 0) {
            int tot = 0;
            for (int wv = 0; wv < 16; ++wv) tot += wsum[wv];
            carry_s += tot;
        }
        __syncthreads();
    }
    if (threadIdx.x == 0) off[n] = carry_s;
}

__global__ void k_fill(const int* __restrict__ src, const int* __restrict__ dst,
                       const int* __restrict__ off, int* __restrict__ cursor,
                       int* __restrict__ eSrc, int E) {
    int e = blockIdx.x * TB + threadIdx.x;
    if (e >= E) return;
    int d = dst[e];
    int pos = off[d] + atomicAdd(&cursor[d], 1);
    eSrc[pos] = src[e];
}

// ---- dense GEMMs (epilogue scales row by dinv[r]) -----------------------

__global__ void k_gemm_x64(const float* __restrict__ X, const float* __restrict__ W,
                           const float* __restrict__ dinv, float* __restrict__ Y, int n) {
    __shared__ float Ws[64 * 64];
    for (int i = threadIdx.x; i < 64 * 64; i += TB) Ws[i] = W[i];
    __syncthreads();
    int c = threadIdx.x & 63;
    int r = blockIdx.x * 4 + (threadIdx.x >> 6);
    if (r >= n) return;
    const float* x = X + (size_t)r * 64;
    float acc = 0.f;
#pragma unroll
    for (int k = 0; k < 64; ++k) acc = fmaf(x[k], Ws[k * 64 + c], acc);
    Y[(size_t)r * 64 + c] = acc * dinv[r];
}

__global__ void k_gemm_64_32(const float* __restrict__ X, const float* __restrict__ W,
                             const float* __restrict__ dinv, float* __restrict__ Y, int n) {
    __shared__ float Ws[64 * 32];
    for (int i = threadIdx.x; i < 64 * 32; i += TB) Ws[i] = W[i];
    __syncthreads();
    int c = threadIdx.x & 31;
    int r = blockIdx.x * 8 + (threadIdx.x >> 5);
    if (r >= n) return;
    const float* x = X + (size_t)r * 64;
    float acc = 0.f;
#pragma unroll
    for (int k = 0; k < 64; ++k) acc = fmaf(x[k], Ws[k * 32 + c], acc);
    Y[(size_t)r * 32 + c] = acc * dinv[r];
}

// ---- gather aggregation on pre-scaled H' (= dinv .* H) -------------------
// out[i] = relu?( (sum_{s in N(i)} H'[s] + H'[i]) * dinv[i] + b )
// k_agg64: wave per node; lane = (slot 0..3, feat4 0..15); 4 edges in flight.

__global__ void k_agg64(const float4* __restrict__ H4, const int* __restrict__ off,
                        const int* __restrict__ eSrc, const float* __restrict__ dinv,
                        const float4* __restrict__ b4, float4* __restrict__ out4, int n) {
    int node = blockIdx.x * 4 + (threadIdx.x >> 6);
    if (node >= n) return;
    int lane = threadIdx.x & 63;
    int feat4 = lane & 15;
    int slot = lane >> 4;
    int j0 = off[node], j1 = off[node + 1];
    float4 acc = make_float4(0.f, 0.f, 0.f, 0.f);
    for (int e = j0 + slot; e < j1; e += 4) {
        int s = eSrc[e];
        float4 v = H4[(size_t)s * 16 + feat4];
        acc.x += v.x; acc.y += v.y; acc.z += v.z; acc.w += v.w;
    }
#pragma unroll
    for (int ofs = 16; ofs < 64; ofs <<= 1) {
        acc.x += __shfl_xor(acc.x, ofs, 64);
        acc.y += __shfl_xor(acc.y, ofs, 64);
        acc.z += __shfl_xor(acc.z, ofs, 64);
        acc.w += __shfl_xor(acc.w, ofs, 64);
    }
    if (slot == 0) {
        float4 self = H4[(size_t)node * 16 + feat4];
        float dv = dinv[node];
        float4 bb = b4[feat4];
        float4 r;
        r.x = fmaxf(fmaf(acc.x + self.x, dv, bb.x), 0.f);
        r.y = fmaxf(fmaf(acc.y + self.y, dv, bb.y), 0.f);
        r.z = fmaxf(fmaf(acc.z + self.z, dv, bb.z), 0.f);
        r.w = fmaxf(fmaf(acc.w + self.w, dv, bb.w), 0.f);
        out4[(size_t)node * 16 + feat4] = r;
    }
}

// k_agg32: wave per node; lane = (slot 0..7, feat4 0..7); 8 edges in flight.
__global__ void k_agg32(const float4* __restrict__ H4, const int* __restrict__ off,
                        const int* __restrict__ eSrc, const float* __restrict__ dinv,
                        const float4* __restrict__ b4, float4* __restrict__ out4, int n) {
    int node = blockIdx.x * 4 + (threadIdx.x >> 6);
    if (node >= n) return;
    int lane = threadIdx.x & 63;
    int feat4 = lane & 7;
    int slot = lane >> 3;
    int j0 = off[node], j1 = off[node + 1];
    float4 acc = make_float4(0.f, 0.f, 0.f, 0.f);
    for (int e = j0 + slot; e < j1; e += 8) {
        int s = eSrc[e];
        float4 v = H4[(size_t)s * 8 + feat4];
        acc.x += v.x; acc.y += v.y; acc.z += v.z; acc.w += v.w;
    }
#pragma unroll
    for (int ofs = 8; ofs < 64; ofs <<= 1) {
        acc.x += __shfl_xor(acc.x, ofs, 64);
        acc.y += __shfl_xor(acc.y, ofs, 64);
        acc.z += __shfl_xor(acc.z, ofs, 64);
        acc.w += __shfl_xor(acc.w, ofs, 64);
    }
    if (slot == 0) {
        float4 self = H4[(size_t)node * 8 + feat4];
        float dv = dinv[node];
        float4 bb = b4[feat4];
        float4 r;
        r.x = fmaf(acc.x + self.x, dv, bb.x);
        r.y = fmaf(acc.y + self.y, dv, bb.y);
        r.z = fmaf(acc.z + self.z, dv, bb.z);
        r.w = fmaf(acc.w + self.w, dv, bb.w);
        out4[(size_t)node * 8 + feat4] = r;
    }
}

// ---- FC: Y[n,1024] = X[n,32] @ W[32,1024] + bias ------------------------

__global__ __launch_bounds__(TB, 4)
void k_fc2(const float* __restrict__ X, const float* __restrict__ W,
           const float* __restrict__ bias, float* __restrict__ Y, int n) {
    __shared__ float Xs[FC_ROWS * 32];
    int c0 = blockIdx.x * 512 + threadIdx.x;  // second column = c0 + 256
    int r0 = blockIdx.y * FC_ROWS;
    int rows = min(FC_ROWS, n - r0);

    float w0[32], w1[32];
#pragma unroll
    for (int k = 0; k < 32; ++k) {
        w0[k] = W[k * 1024 + c0];
        w1[k] = W[k * 1024 + c0 + 256];
    }
    float b0 = bias[c0], b1 = bias[c0 + 256];

    {
        const float4* Xg = (const float4*)(X + (size_t)r0 * 32);
        float4* Xs4 = (float4*)Xs;
        int tot4 = rows * 8;
        for (int i = threadIdx.x; i < tot4; i += TB) Xs4[i] = Xg[i];
    }
    __syncthreads();

    for (int r = 0; r < rows; ++r) {
        const float* x = Xs + r * 32;
        float a0 = b0, a1 = b1;
#pragma unroll
        for (int k = 0; k < 32; ++k) {
            float xv = x[k];
            a0 = fmaf(xv, w0[k], a0);
            a1 = fmaf(xv, w1[k], a1);
        }
        size_t o = (size_t)(r0 + r) * 1024;
        __builtin_nontemporal_store(a0, &Y[o + c0]);
        __builtin_nontemporal_store(a1, &Y[o + c0 + 256]);
    }
}

// ---- launch -------------------------------------------------------------

extern "C" void kernel_launch(void* const* d_in, const int* in_sizes, int n_in,
                              void* d_out, int out_size, void* d_ws, size_t ws_size,
                              hipStream_t stream) {
    const float* z   = (const float*)d_in[0];
    const int*   ei  = (const int*)d_in[1];
    const float* W1  = (const float*)d_in[2];
    const float* b1  = (const float*)d_in[3];
    const float* W2  = (const float*)d_in[4];
    const float* b2  = (const float*)d_in[5];
    const float* Wfc = (const float*)d_in[6];
    const float* bfc = (const float*)d_in[7];
    float* out = (float*)d_out;

    int n = in_sizes[0] / 64;
    int E = in_sizes[1] / 2;
    const int* src = ei;
    const int* dst = ei + E;

    // Workspace layout (4-byte words):
    //   cnt[n] | cursor[n] | off[n+1] | eSrc[E] | dinv[n] | bufA[n*64] | bufB[n*64]
    int* cnt    = (int*)d_ws;
    int* cursor = cnt + n;
    int* off    = cursor + n;
    int* eSrc   = off + (n + 1);
    float* dinv = (float*)(eSrc + E);
    float* bufA = dinv + n;
    float* bufB = bufA + (size_t)n * 64;
    float* h2   = bufA;
    float* agg2 = bufA + (size_t)n * 32;

    // ---- CSR build + norms ----
    {
        int n4 = (2 * n + 3) / 4;  // may clobber off[0..2]; scan rewrites off later
        k_zero<<<(n4 + TB - 1) / TB, TB, 0, stream>>>((int4*)cnt, n4);
    }
    k_hist<<<(E + TB - 1) / TB, TB, 0, stream>>>(dst, cnt, E);
    k_dinv<<<(n + TB - 1) / TB, TB, 0, stream>>>(cnt, dinv, n);
    k_scan<<<1, 1024, 0, stream>>>(cnt, off, n);
    k_fill<<<(E + TB - 1) / TB, TB, 0, stream>>>(src, dst, off, cursor, eSrc, E);

    // ---- conv1: h1' = dinv .* (z @ W1) ; gather-agg (+b1, relu) -> bufB ----
    k_gemm_x64<<<(n + 3) / 4, TB, 0, stream>>>(z, W1, dinv, bufA, n);
    k_agg64<<<(n + 3) / 4, TB, 0, stream>>>((const float4*)bufA, off, eSrc, dinv,
                                            (const float4*)b1, (float4*)bufB, n);

    // ---- conv2: h2' = dinv .* (bufB @ W2) ; gather-agg (+b2) -> agg2 ----
    k_gemm_64_32<<<(n + 7) / 8, TB, 0, stream>>>(bufB, W2, dinv, h2, n);
    k_agg32<<<(n + 3) / 4, TB, 0, stream>>>((const float4*)h2, off, eSrc, dinv,
                                            (const float4*)b2, (float4*)agg2, n);

    // ---- fc: out = agg2 @ Wfc + bfc ----
    {
        dim3 grid(2, (n + FC_ROWS - 1) / FC_ROWS);
        k_fc2<<<grid, TB, 0, stream>>>(agg2, Wfc, bfc, out, n);
    }
}

// Round 6
// 257.859 us; speedup vs baseline: 2.7985x; 1.1147x over previous
//
#include <hip/hip_runtime.h>

// GCN decoder: 2x GCNConv (self-loops, symmetric norm) + FC to 1024.
// n = 50000 nodes, E = 800000 directed edges, feats 64 -> 64 -> 32 -> 1024.
// Round 6: 3-phase parallel scan (dinv fused); cursor-free CSR fill
//          (count-down atomics); GEMMs 4x rows/block with X in LDS;
//          FC float2 weight/store layout.

#define TB 256
#define FC_ROWS 64
#define SCHUNK 4096  // scan elements per block (1024 thr x 4)

typedef __attribute__((ext_vector_type(2))) float f32x2;

// ---- utility ------------------------------------------------------------

__global__ void k_zero(int4* __restrict__ p, int n4) {
    int i = blockIdx.x * TB + threadIdx.x;
    if (i < n4) p[i] = make_int4(0, 0, 0, 0);
}

// ---- CSR build ----------------------------------------------------------

__global__ void k_hist(const int* __restrict__ dst, int* __restrict__ cnt, int E) {
    int e = blockIdx.x * TB + threadIdx.x;
    if (e < E) atomicAdd(&cnt[dst[e]], 1);
}

// Phase 1: per-chunk exclusive scan (local) + chunk totals; dinv fused.
__global__ __launch_bounds__(1024)
void k_scan1(const int* __restrict__ cnt, int* __restrict__ off,
             float* __restrict__ dinv, int* __restrict__ bsum, int n) {
    __shared__ int wsum[16];
    int base = blockIdx.x * SCHUNK;
    int i4 = base + threadIdx.x * 4;
    int lane = threadIdx.x & 63, wid = threadIdx.x >> 6;
    int v0 = 0, v1 = 0, v2 = 0, v3 = 0;
    if (i4 + 3 < n) {
        int4 t = *(const int4*)(cnt + i4);
        v0 = t.x; v1 = t.y; v2 = t.z; v3 = t.w;
    } else {
        if (i4 < n) v0 = cnt[i4];
        if (i4 + 1 < n) v1 = cnt[i4 + 1];
        if (i4 + 2 < n) v2 = cnt[i4 + 2];
        if (i4 + 3 < n) v3 = cnt[i4 + 3];
    }
    int s = v0 + v1 + v2 + v3;
    int x = s;
#pragma unroll
    for (int ofs = 1; ofs < 64; ofs <<= 1) {
        int t = __shfl_up(x, ofs, 64);
        if (lane >= ofs) x += t;
    }
    if (lane == 63) wsum[wid] = x;
    __syncthreads();
    int wp = 0;
#pragma unroll
    for (int wv = 0; wv < 16; ++wv) wp += (wv < wid) ? wsum[wv] : 0;
    int excl = wp + x - s;
    if (i4 < n)     { off[i4]     = excl;                dinv[i4]     = rsqrtf((float)(v0 + 1)); }
    if (i4 + 1 < n) { off[i4 + 1] = excl + v0;           dinv[i4 + 1] = rsqrtf((float)(v1 + 1)); }
    if (i4 + 2 < n) { off[i4 + 2] = excl + v0 + v1;      dinv[i4 + 2] = rsqrtf((float)(v2 + 1)); }
    if (i4 + 3 < n) { off[i4 + 3] = excl + v0 + v1 + v2; dinv[i4 + 3] = rsqrtf((float)(v3 + 1)); }
    if (threadIdx.x == 0) {
        int tot = 0;
#pragma unroll
        for (int wv = 0; wv < 16; ++wv) tot += wsum[wv];
        bsum[blockIdx.x] = tot;
    }
}

// Phase 2: single wave scans the chunk totals (exclusive, in place).
__global__ void k_scan2(int* __restrict__ bsum, int* __restrict__ off, int nb, int n, int E) {
    int lane = threadIdx.x;
    int v = (lane < nb) ? bsum[lane] : 0;
    int x = v;
#pragma unroll
    for (int ofs = 1; ofs < 64; ofs <<= 1) {
        int t = __shfl_up(x, ofs, 64);
        if (lane >= ofs) x += t;
    }
    if (lane < nb) bsum[lane] = x - v;
    if (lane == 0) off[n] = E;
}

// Phase 3: add chunk prefix.
__global__ void k_scan3(int* __restrict__ off, const int* __restrict__ bsum, int n) {
    int i = blockIdx.x * TB + threadIdx.x;
    if (i < n) off[i] += bsum[i >> 12];  // SCHUNK = 4096 = 1<<12
}

// Fill CSR lists; slot allocation by counting cnt down (no cursor buffer).
__global__ void k_fill(const int* __restrict__ src, const int* __restrict__ dst,
                       const int* __restrict__ off, int* __restrict__ cnt,
                       int* __restrict__ eSrc, int E) {
    int e = blockIdx.x * TB + threadIdx.x;
    if (e >= E) return;
    int d = dst[e];
    int pos = off[d] + atomicSub(&cnt[d], 1) - 1;
    eSrc[pos] = src[e];
}

// ---- dense GEMMs (epilogue scales row by dinv[r]) -----------------------

// Y[r,c] = dinv[r] * sum_k X[r,k] W[k,c]; 64x64 W + 16 X rows in LDS.
__global__ void k_gemm_x64(const float* __restrict__ X, const float* __restrict__ W,
                           const float* __restrict__ dinv, float* __restrict__ Y, int n) {
    __shared__ float Ws[64 * 64];
    __shared__ float Xs[16 * 64];
    for (int i = threadIdx.x; i < 64 * 64; i += TB) Ws[i] = W[i];
    int r0 = blockIdx.x * 16;
    int rows = min(16, n - r0);
    {
        const float4* Xg = (const float4*)(X + (size_t)r0 * 64);
        float4* Xs4 = (float4*)Xs;
        int tot4 = rows * 16;
        for (int i = threadIdx.x; i < tot4; i += TB) Xs4[i] = Xg[i];
    }
    __syncthreads();
    int c = threadIdx.x & 63;
    int g = threadIdx.x >> 6;  // 0..3
#pragma unroll
    for (int rr = 0; rr < 4; ++rr) {
        int rb = g + rr * 4;
        int r = r0 + rb;
        if (r >= n) break;
        const float* x = Xs + rb * 64;
        float acc = 0.f;
#pragma unroll
        for (int k = 0; k < 64; ++k) acc = fmaf(x[k], Ws[k * 64 + c], acc);
        Y[(size_t)r * 64 + c] = acc * dinv[r];
    }
}

// Y[r,c] = dinv[r] * sum_k X[r,k] W[k,c]; 64x32 W + 32 X rows in LDS.
__global__ void k_gemm_64_32(const float* __restrict__ X, const float* __restrict__ W,
                             const float* __restrict__ dinv, float* __restrict__ Y, int n) {
    __shared__ float Ws[64 * 32];
    __shared__ float Xs[32 * 64];
    for (int i = threadIdx.x; i < 64 * 32; i += TB) Ws[i] = W[i];
    int r0 = blockIdx.x * 32;
    int rows = min(32, n - r0);
    {
        const float4* Xg = (const float4*)(X + (size_t)r0 * 64);
        float4* Xs4 = (float4*)Xs;
        int tot4 = rows * 16;
        for (int i = threadIdx.x; i < tot4; i += TB) Xs4[i] = Xg[i];
    }
    __syncthreads();
    int c = threadIdx.x & 31;
    int g = threadIdx.x >> 5;  // 0..7
#pragma unroll
    for (int rr = 0; rr < 4; ++rr) {
        int rb = g + rr * 8;
        int r = r0 + rb;
        if (r >= n) break;
        const float* x = Xs + rb * 64;
        float acc = 0.f;
#pragma unroll
        for (int k = 0; k < 64; ++k) acc = fmaf(x[k], Ws[k * 32 + c], acc);
        Y[(size_t)r * 32 + c] = acc * dinv[r];
    }
}

// ---- gather aggregation on pre-scaled H' (= dinv .* H) -------------------
// out[i] = relu?( (sum_{s in N(i)} H'[s] + H'[i]) * dinv[i] + b )

__global__ void k_agg64(const float4* __restrict__ H4, const int* __restrict__ off,
                        const int* __restrict__ eSrc, const float* __restrict__ dinv,
                        const float4* __restrict__ b4, float4* __restrict__ out4, int n) {
    int node = blockIdx.x * 4 + (threadIdx.x >> 6);
    if (node >= n) return;
    int lane = threadIdx.x & 63;
    int feat4 = lane & 15;
    int slot = lane >> 4;
    int j0 = off[node], j1 = off[node + 1];
    float4 acc = make_float4(0.f, 0.f, 0.f, 0.f);
    for (int e = j0 + slot; e < j1; e += 4) {
        int s = eSrc[e];
        float4 v = H4[(size_t)s * 16 + feat4];
        acc.x += v.x; acc.y += v.y; acc.z += v.z; acc.w += v.w;
    }
#pragma unroll
    for (int ofs = 16; ofs < 64; ofs <<= 1) {
        acc.x += __shfl_xor(acc.x, ofs, 64);
        acc.y += __shfl_xor(acc.y, ofs, 64);
        acc.z += __shfl_xor(acc.z, ofs, 64);
        acc.w += __shfl_xor(acc.w, ofs, 64);
    }
    if (slot == 0) {
        float4 self = H4[(size_t)node * 16 + feat4];
        float dv = dinv[node];
        float4 bb = b4[feat4];
        float4 r;
        r.x = fmaxf(fmaf(acc.x + self.x, dv, bb.x), 0.f);
        r.y = fmaxf(fmaf(acc.y + self.y, dv, bb.y), 0.f);
        r.z = fmaxf(fmaf(acc.z + self.z, dv, bb.z), 0.f);
        r.w = fmaxf(fmaf(acc.w + self.w, dv, bb.w), 0.f);
        out4[(size_t)node * 16 + feat4] = r;
    }
}

__global__ void k_agg32(const float4* __restrict__ H4, const int* __restrict__ off,
                        const int* __restrict__ eSrc, const float* __restrict__ dinv,
                        const float4* __restrict__ b4, float4* __restrict__ out4, int n) {
    int node = blockIdx.x * 4 + (threadIdx.x >> 6);
    if (node >= n) return;
    int lane = threadIdx.x & 63;
    int feat4 = lane & 7;
    int slot = lane >> 3;
    int j0 = off[node], j1 = off[node + 1];
    float4 acc = make_float4(0.f, 0.f, 0.f, 0.f);
    for (int e = j0 + slot; e < j1; e += 8) {
        int s = eSrc[e];
        float4 v = H4[(size_t)s * 8 + feat4];
        acc.x += v.x; acc.y += v.y; acc.z += v.z; acc.w += v.w;
    }
#pragma unroll
    for (int ofs = 8; ofs < 64; ofs <<= 1) {
        acc.x += __shfl_xor(acc.x, ofs, 64);
        acc.y += __shfl_xor(acc.y, ofs, 64);
        acc.z += __shfl_xor(acc.z, ofs, 64);
        acc.w += __shfl_xor(acc.w, ofs, 64);
    }
    if (slot == 0) {
        float4 self = H4[(size_t)node * 8 + feat4];
        float dv = dinv[node];
        float4 bb = b4[feat4];
        float4 r;
        r.x = fmaf(acc.x + self.x, dv, bb.x);
        r.y = fmaf(acc.y + self.y, dv, bb.y);
        r.z = fmaf(acc.z + self.z, dv, bb.z);
        r.w = fmaf(acc.w + self.w, dv, bb.w);
        out4[(size_t)node * 8 + feat4] = r;
    }
}

// ---- FC: Y[n,1024] = X[n,32] @ W[32,1024] + bias ------------------------
// Thread owns 2 adjacent W columns in 64 VGPRs; float2 nt stores.
__global__ __launch_bounds__(TB, 4)
void k_fc2(const float* __restrict__ X, const float* __restrict__ W,
           const float* __restrict__ bias, float* __restrict__ Y, int n) {
    __shared__ float Xs[FC_ROWS * 32];
    int c0 = (blockIdx.x * TB + threadIdx.x) * 2;  // grid.x = 2 covers 1024 cols
    int r0 = blockIdx.y * FC_ROWS;
    int rows = min(FC_ROWS, n - r0);

    f32x2 w[32];
#pragma unroll
    for (int k = 0; k < 32; ++k) w[k] = *(const f32x2*)(W + k * 1024 + c0);
    f32x2 bb = *(const f32x2*)(bias + c0);

    {
        const float4* Xg = (const float4*)(X + (size_t)r0 * 32);
        float4* Xs4 = (float4*)Xs;
        int tot4 = rows * 8;
        for (int i = threadIdx.x; i < tot4; i += TB) Xs4[i] = Xg[i];
    }
    __syncthreads();

    for (int r = 0; r < rows; ++r) {
        const float* x = Xs + r * 32;
        float a0 = bb.x, a1 = bb.y;
#pragma unroll
        for (int k = 0; k < 32; ++k) {
            float xv = x[k];
            a0 = fmaf(xv, w[k].x, a0);
            a1 = fmaf(xv, w[k].y, a1);
        }
        f32x2 v; v.x = a0; v.y = a1;
        __builtin_nontemporal_store(v, (f32x2*)(Y + (size_t)(r0 + r) * 1024 + c0));
    }
}

// ---- launch -------------------------------------------------------------

extern "C" void kernel_launch(void* const* d_in, const int* in_sizes, int n_in,
                              void* d_out, int out_size, void* d_ws, size_t ws_size,
                              hipStream_t stream) {
    const float* z   = (const float*)d_in[0];
    const int*   ei  = (const int*)d_in[1];
    const float* W1  = (const float*)d_in[2];
    const float* b1  = (const float*)d_in[3];
    const float* W2  = (const float*)d_in[4];
    const float* b2  = (const float*)d_in[5];
    const float* Wfc = (const float*)d_in[6];
    const float* bfc = (const float*)d_in[7];
    float* out = (float*)d_out;

    int n = in_sizes[0] / 64;
    int E = in_sizes[1] / 2;
    const int* src = ei;
    const int* dst = ei + E;

    // Workspace layout (4-byte words):
    //   cnt[n] | bsum[64] | off[n+1] | eSrc[E] | dinv[n] | bufA[n*64] | bufB[n*64]
    int* cnt    = (int*)d_ws;
    int* bsum   = cnt + n;
    int* off    = bsum + 64;
    int* eSrc   = off + (n + 1);
    float* dinv = (float*)(eSrc + E);
    float* bufA = dinv + n;
    float* bufB = bufA + (size_t)n * 64;
    float* h2   = bufA;
    float* agg2 = bufA + (size_t)n * 32;

    int nChunks = (n + SCHUNK - 1) / SCHUNK;

    // ---- CSR build + norms ----
    {
        int n4 = (n + 3) / 4;
        k_zero<<<(n4 + TB - 1) / TB, TB, 0, stream>>>((int4*)cnt, n4);
    }
    k_hist<<<(E + TB - 1) / TB, TB, 0, stream>>>(dst, cnt, E);
    k_scan1<<<nChunks, 1024, 0, stream>>>(cnt, off, dinv, bsum, n);
    k_scan2<<<1, 64, 0, stream>>>(bsum, off, nChunks, n, E);
    k_scan3<<<(n + TB - 1) / TB, TB, 0, stream>>>(off, bsum, n);
    k_fill<<<(E + TB - 1) / TB, TB, 0, stream>>>(src, dst, off, cnt, eSrc, E);

    // ---- conv1: h1' = dinv .* (z @ W1) ; gather-agg (+b1, relu) -> bufB ----
    k_gemm_x64<<<(n + 15) / 16, TB, 0, stream>>>(z, W1, dinv, bufA, n);
    k_agg64<<<(n + 3) / 4, TB, 0, stream>>>((const float4*)bufA, off, eSrc, dinv,
                                            (const float4*)b1, (float4*)bufB, n);

    // ---- conv2: h2' = dinv .* (bufB @ W2) ; gather-agg (+b2) -> agg2 ----
    k_gemm_64_32<<<(n + 31) / 32, TB, 0, stream>>>(bufB, W2, dinv, h2, n);
    k_agg32<<<(n + 3) / 4, TB, 0, stream>>>((const float4*)h2, off, eSrc, dinv,
                                            (const float4*)b2, (float4*)agg2, n);

    // ---- fc: out = agg2 @ Wfc + bfc ----
    {
        dim3 grid(2, (n + FC_ROWS - 1) / FC_ROWS);
        k_fc2<<<grid, TB, 0, stream>>>(agg2, Wfc, bfc, out, n);
    }
}

// Round 8
// 230.491 us; speedup vs baseline: 3.1308x; 1.1187x over previous
//
#include <hip/hip_runtime.h>

// GCN decoder: 2x GCNConv (self-loops, symmetric norm) + FC to 1024.
// n = 50000 nodes, E = 800000 directed edges, feats 64 -> 64 -> 32 -> 1024.
// Round 8: round-7 plan with the nt-store fixed (ext_vector_type f32x4 --
//          __builtin_nontemporal_store rejects HIP_vector_type float4).

#define TB 256
#define FC_ROWS 64
#define SCHUNK 4096  // scan elements per block (1024 thr x 4)

typedef __attribute__((ext_vector_type(4))) float f32x4;

// ---- utility ------------------------------------------------------------

__global__ void k_zero(int4* __restrict__ p, int n4) {
    int i = blockIdx.x * TB + threadIdx.x;
    if (i < n4) p[i] = make_int4(0, 0, 0, 0);
}

// ---- CSR build ----------------------------------------------------------

// Count in-degree; record each edge's slot within its dst list.
__global__ void k_hist(const int* __restrict__ dst, int* __restrict__ cnt,
                       int* __restrict__ slot, int E) {
    int e = blockIdx.x * TB + threadIdx.x;
    if (e < E) slot[e] = atomicAdd(&cnt[dst[e]], 1);
}

// Phase 1: per-chunk exclusive scan (local) + chunk totals; dinv fused.
__global__ __launch_bounds__(1024)
void k_scan1(const int* __restrict__ cnt, int* __restrict__ off,
             float* __restrict__ dinv, int* __restrict__ bsum, int n) {
    __shared__ int wsum[16];
    int base = blockIdx.x * SCHUNK;
    int i4 = base + threadIdx.x * 4;
    int lane = threadIdx.x & 63, wid = threadIdx.x >> 6;
    int v0 = 0, v1 = 0, v2 = 0, v3 = 0;
    if (i4 + 3 < n) {
        int4 t = *(const int4*)(cnt + i4);
        v0 = t.x; v1 = t.y; v2 = t.z; v3 = t.w;
    } else {
        if (i4 < n) v0 = cnt[i4];
        if (i4 + 1 < n) v1 = cnt[i4 + 1];
        if (i4 + 2 < n) v2 = cnt[i4 + 2];
        if (i4 + 3 < n) v3 = cnt[i4 + 3];
    }
    int s = v0 + v1 + v2 + v3;
    int x = s;
#pragma unroll
    for (int ofs = 1; ofs < 64; ofs <<= 1) {
        int t = __shfl_up(x, ofs, 64);
        if (lane >= ofs) x += t;
    }
    if (lane == 63) wsum[wid] = x;
    __syncthreads();
    int wp = 0;
#pragma unroll
    for (int wv = 0; wv < 16; ++wv) wp += (wv < wid) ? wsum[wv] : 0;
    int excl = wp + x - s;
    if (i4 < n)     { off[i4]     = excl;                dinv[i4]     = rsqrtf((float)(v0 + 1)); }
    if (i4 + 1 < n) { off[i4 + 1] = excl + v0;           dinv[i4 + 1] = rsqrtf((float)(v1 + 1)); }
    if (i4 + 2 < n) { off[i4 + 2] = excl + v0 + v1;      dinv[i4 + 2] = rsqrtf((float)(v2 + 1)); }
    if (i4 + 3 < n) { off[i4 + 3] = excl + v0 + v1 + v2; dinv[i4 + 3] = rsqrtf((float)(v3 + 1)); }
    if (threadIdx.x == 0) {
        int tot = 0;
#pragma unroll
        for (int wv = 0; wv < 16; ++wv) tot += wsum[wv];
        bsum[blockIdx.x] = tot;
    }
}

// Phase 2: add chunk prefix (computed per block; <=13 chunks) ; off[n]=E.
__global__ void k_scan3(int* __restrict__ off, const int* __restrict__ bsum,
                        int n, int E) {
    __shared__ int pfx_s;
    int i = blockIdx.x * TB + threadIdx.x;
    if (threadIdx.x == 0) {
        int chunk = (blockIdx.x * TB) >> 12;  // SCHUNK = 4096; constant per block
        int s = 0;
        for (int j = 0; j < chunk; ++j) s += bsum[j];
        pfx_s = s;
    }
    __syncthreads();
    if (i < n) off[i] += pfx_s;
    if (i == 0) off[n] = E;
}

// Atomic-free fill: position = off[dst] + slot (recorded by hist).
__global__ void k_fill(const int* __restrict__ src, const int* __restrict__ dst,
                       const int* __restrict__ off, const int* __restrict__ slot,
                       int* __restrict__ eSrc, int E) {
    int e = blockIdx.x * TB + threadIdx.x;
    if (e >= E) return;
    eSrc[off[dst[e]] + slot[e]] = src[e];
}

// ---- dense GEMMs (epilogue scales row by dinv[r]) -----------------------

__global__ void k_gemm_x64(const float* __restrict__ X, const float* __restrict__ W,
                           const float* __restrict__ dinv, float* __restrict__ Y, int n) {
    __shared__ float Ws[64 * 64];
    __shared__ float Xs[16 * 64];
    for (int i = threadIdx.x; i < 64 * 64; i += TB) Ws[i] = W[i];
    int r0 = blockIdx.x * 16;
    int rows = min(16, n - r0);
    {
        const float4* Xg = (const float4*)(X + (size_t)r0 * 64);
        float4* Xs4 = (float4*)Xs;
        int tot4 = rows * 16;
        for (int i = threadIdx.x; i < tot4; i += TB) Xs4[i] = Xg[i];
    }
    __syncthreads();
    int c = threadIdx.x & 63;
    int g = threadIdx.x >> 6;  // 0..3
#pragma unroll
    for (int rr = 0; rr < 4; ++rr) {
        int rb = g + rr * 4;
        int r = r0 + rb;
        if (r >= n) break;
        const float* x = Xs + rb * 64;
        float acc = 0.f;
#pragma unroll
        for (int k = 0; k < 64; ++k) acc = fmaf(x[k], Ws[k * 64 + c], acc);
        Y[(size_t)r * 64 + c] = acc * dinv[r];
    }
}

__global__ void k_gemm_64_32(const float* __restrict__ X, const float* __restrict__ W,
                             const float* __restrict__ dinv, float* __restrict__ Y, int n) {
    __shared__ float Ws[64 * 32];
    __shared__ float Xs[32 * 64];
    for (int i = threadIdx.x; i < 64 * 32; i += TB) Ws[i] = W[i];
    int r0 = blockIdx.x * 32;
    int rows = min(32, n - r0);
    {
        const float4* Xg = (const float4*)(X + (size_t)r0 * 64);
        float4* Xs4 = (float4*)Xs;
        int tot4 = rows * 16;
        for (int i = threadIdx.x; i < tot4; i += TB) Xs4[i] = Xg[i];
    }
    __syncthreads();
    int c = threadIdx.x & 31;
    int g = threadIdx.x >> 5;  // 0..7
#pragma unroll
    for (int rr = 0; rr < 4; ++rr) {
        int rb = g + rr * 8;
        int r = r0 + rb;
        if (r >= n) break;
        const float* x = Xs + rb * 64;
        float acc = 0.f;
#pragma unroll
        for (int k = 0; k < 64; ++k) acc = fmaf(x[k], Ws[k * 32 + c], acc);
        Y[(size_t)r * 32 + c] = acc * dinv[r];
    }
}

// ---- gather aggregation on pre-scaled H' (= dinv .* H) -------------------
// out[i] = relu?( (sum_{s in N(i)} H'[s] + H'[i]) * dinv[i] + b )
// agg64: wave per node; lane = (slot 0..7, feat4 0..7); 2 gathers/lane
// (feat4, feat4+8) -> 8 edges x 2 loads = 16 outstanding per wave.

__global__ void k_agg64(const float4* __restrict__ H4, const int* __restrict__ off,
                        const int* __restrict__ eSrc, const float* __restrict__ dinv,
                        const float4* __restrict__ b4, float4* __restrict__ out4, int n) {
    int node = blockIdx.x * 4 + (threadIdx.x >> 6);
    if (node >= n) return;
    int lane = threadIdx.x & 63;
    int feat4 = lane & 7;
    int slot = lane >> 3;
    int j0 = off[node], j1 = off[node + 1];
    float4 lo = make_float4(0.f, 0.f, 0.f, 0.f);
    float4 hi = make_float4(0.f, 0.f, 0.f, 0.f);
    for (int e = j0 + slot; e < j1; e += 8) {
        int s = eSrc[e];
        float4 a = H4[(size_t)s * 16 + feat4];
        float4 b = H4[(size_t)s * 16 + 8 + feat4];
        lo.x += a.x; lo.y += a.y; lo.z += a.z; lo.w += a.w;
        hi.x += b.x; hi.y += b.y; hi.z += b.z; hi.w += b.w;
    }
#pragma unroll
    for (int ofs = 8; ofs < 64; ofs <<= 1) {
        lo.x += __shfl_xor(lo.x, ofs, 64);
        lo.y += __shfl_xor(lo.y, ofs, 64);
        lo.z += __shfl_xor(lo.z, ofs, 64);
        lo.w += __shfl_xor(lo.w, ofs, 64);
        hi.x += __shfl_xor(hi.x, ofs, 64);
        hi.y += __shfl_xor(hi.y, ofs, 64);
        hi.z += __shfl_xor(hi.z, ofs, 64);
        hi.w += __shfl_xor(hi.w, ofs, 64);
    }
    if (slot == 0) {
        float dv = dinv[node];
        float4 s0 = H4[(size_t)node * 16 + feat4];
        float4 s1 = H4[(size_t)node * 16 + 8 + feat4];
        float4 c0 = b4[feat4];
        float4 c1 = b4[feat4 + 8];
        float4 r0, r1;
        r0.x = fmaxf(fmaf(lo.x + s0.x, dv, c0.x), 0.f);
        r0.y = fmaxf(fmaf(lo.y + s0.y, dv, c0.y), 0.f);
        r0.z = fmaxf(fmaf(lo.z + s0.z, dv, c0.z), 0.f);
        r0.w = fmaxf(fmaf(lo.w + s0.w, dv, c0.w), 0.f);
        r1.x = fmaxf(fmaf(hi.x + s1.x, dv, c1.x), 0.f);
        r1.y = fmaxf(fmaf(hi.y + s1.y, dv, c1.y), 0.f);
        r1.z = fmaxf(fmaf(hi.z + s1.z, dv, c1.z), 0.f);
        r1.w = fmaxf(fmaf(hi.w + s1.w, dv, c1.w), 0.f);
        out4[(size_t)node * 16 + feat4] = r0;
        out4[(size_t)node * 16 + 8 + feat4] = r1;
    }
}

// agg32: wave per node; lane = (slot 0..15, feat4 0..3); 2 gathers/lane
// (feat4, feat4+4) -> 16 edges in flight.
__global__ void k_agg32(const float4* __restrict__ H4, const int* __restrict__ off,
                        const int* __restrict__ eSrc, const float* __restrict__ dinv,
                        const float4* __restrict__ b4, float4* __restrict__ out4, int n) {
    int node = blockIdx.x * 4 + (threadIdx.x >> 6);
    if (node >= n) return;
    int lane = threadIdx.x & 63;
    int feat4 = lane & 3;
    int slot = lane >> 2;
    int j0 = off[node], j1 = off[node + 1];
    float4 lo = make_float4(0.f, 0.f, 0.f, 0.f);
    float4 hi = make_float4(0.f, 0.f, 0.f, 0.f);
    for (int e = j0 + slot; e < j1; e += 16) {
        int s = eSrc[e];
        float4 a = H4[(size_t)s * 8 + feat4];
        float4 b = H4[(size_t)s * 8 + 4 + feat4];
        lo.x += a.x; lo.y += a.y; lo.z += a.z; lo.w += a.w;
        hi.x += b.x; hi.y += b.y; hi.z += b.z; hi.w += b.w;
    }
#pragma unroll
    for (int ofs = 4; ofs < 64; ofs <<= 1) {
        lo.x += __shfl_xor(lo.x, ofs, 64);
        lo.y += __shfl_xor(lo.y, ofs, 64);
        lo.z += __shfl_xor(lo.z, ofs, 64);
        lo.w += __shfl_xor(lo.w, ofs, 64);
        hi.x += __shfl_xor(hi.x, ofs, 64);
        hi.y += __shfl_xor(hi.y, ofs, 64);
        hi.z += __shfl_xor(hi.z, ofs, 64);
        hi.w += __shfl_xor(hi.w, ofs, 64);
    }
    if (slot == 0) {
        float dv = dinv[node];
        float4 s0 = H4[(size_t)node * 8 + feat4];
        float4 s1 = H4[(size_t)node * 8 + 4 + feat4];
        float4 c0 = b4[feat4];
        float4 c1 = b4[feat4 + 4];
        float4 r0, r1;
        r0.x = fmaf(lo.x + s0.x, dv, c0.x);
        r0.y = fmaf(lo.y + s0.y, dv, c0.y);
        r0.z = fmaf(lo.z + s0.z, dv, c0.z);
        r0.w = fmaf(lo.w + s0.w, dv, c0.w);
        r1.x = fmaf(hi.x + s1.x, dv, c1.x);
        r1.y = fmaf(hi.y + s1.y, dv, c1.y);
        r1.z = fmaf(hi.z + s1.z, dv, c1.z);
        r1.w = fmaf(hi.w + s1.w, dv, c1.w);
        out4[(size_t)node * 8 + feat4] = r0;
        out4[(size_t)node * 8 + 4 + feat4] = r1;
    }
}

// ---- FC: Y[n,1024] = X[n,32] @ W[32,1024] + bias ------------------------
// Thread owns 4 adjacent W columns (128 VGPRs of weights); f32x4 nt stores.
__global__ __launch_bounds__(TB, 2)
void k_fc2(const float* __restrict__ X, const float* __restrict__ W,
           const float* __restrict__ bias, float* __restrict__ Y, int n) {
    __shared__ float Xs[FC_ROWS * 32];
    int c0 = threadIdx.x * 4;  // 256 threads x 4 = 1024 cols
    int r0 = blockIdx.x * FC_ROWS;
    int rows = min(FC_ROWS, n - r0);

    float4 w[32];
#pragma unroll
    for (int k = 0; k < 32; ++k) w[k] = *(const float4*)(W + k * 1024 + c0);
    float4 bb = *(const float4*)(bias + c0);

    {
        const float4* Xg = (const float4*)(X + (size_t)r0 * 32);
        float4* Xs4 = (float4*)Xs;
        int tot4 = rows * 8;
        for (int i = threadIdx.x; i < tot4; i += TB) Xs4[i] = Xg[i];
    }
    __syncthreads();

    for (int r = 0; r < rows; ++r) {
        const float* x = Xs + r * 32;
        float a0 = bb.x, a1 = bb.y, a2 = bb.z, a3 = bb.w;
#pragma unroll
        for (int k = 0; k < 32; ++k) {
            float xv = x[k];
            a0 = fmaf(xv, w[k].x, a0);
            a1 = fmaf(xv, w[k].y, a1);
            a2 = fmaf(xv, w[k].z, a2);
            a3 = fmaf(xv, w[k].w, a3);
        }
        f32x4 v;
        v.x = a0; v.y = a1; v.z = a2; v.w = a3;
        __builtin_nontemporal_store(v, (f32x4*)(Y + (size_t)(r0 + r) * 1024 + c0));
    }
}

// ---- launch -------------------------------------------------------------

extern "C" void kernel_launch(void* const* d_in, const int* in_sizes, int n_in,
                              void* d_out, int out_size, void* d_ws, size_t ws_size,
                              hipStream_t stream) {
    const float* z   = (const float*)d_in[0];
    const int*   ei  = (const int*)d_in[1];
    const float* W1  = (const float*)d_in[2];
    const float* b1  = (const float*)d_in[3];
    const float* W2  = (const float*)d_in[4];
    const float* b2  = (const float*)d_in[5];
    const float* Wfc = (const float*)d_in[6];
    const float* bfc = (const float*)d_in[7];
    float* out = (float*)d_out;

    int n = in_sizes[0] / 64;
    int E = in_sizes[1] / 2;
    const int* src = ei;
    const int* dst = ei + E;

    // Workspace layout (4-byte words):
    //   cnt[n] | bsum[64] | off[n+1] | slot[E] | eSrc[E] | dinv[n] | bufA[n*64] | bufB[n*64]
    int* cnt    = (int*)d_ws;
    int* bsum   = cnt + n;
    int* off    = bsum + 64;
    int* slot   = off + (n + 1);
    int* eSrc   = slot + E;
    float* dinv = (float*)(eSrc + E);
    float* bufA = dinv + n;
    float* bufB = bufA + (size_t)n * 64;
    float* h2   = bufA;
    float* agg2 = bufA + (size_t)n * 32;

    int nChunks = (n + SCHUNK - 1) / SCHUNK;

    // ---- CSR build + norms ----
    {
        int n4 = (n + 3) / 4;
        k_zero<<<(n4 + TB - 1) / TB, TB, 0, stream>>>((int4*)cnt, n4);
    }
    k_hist<<<(E + TB - 1) / TB, TB, 0, stream>>>(dst, cnt, slot, E);
    k_scan1<<<nChunks, 1024, 0, stream>>>(cnt, off, dinv, bsum, n);
    k_scan3<<<(n + TB - 1) / TB, TB, 0, stream>>>(off, bsum, n, E);
    k_fill<<<(E + TB - 1) / TB, TB, 0, stream>>>(src, dst, off, slot, eSrc, E);

    // ---- conv1: h1' = dinv .* (z @ W1) ; gather-agg (+b1, relu) -> bufB ----
    k_gemm_x64<<<(n + 15) / 16, TB, 0, stream>>>(z, W1, dinv, bufA, n);
    k_agg64<<<(n + 3) / 4, TB, 0, stream>>>((const float4*)bufA, off, eSrc, dinv,
                                            (const float4*)b1, (float4*)bufB, n);

    // ---- conv2: h2' = dinv .* (bufB @ W2) ; gather-agg (+b2) -> agg2 ----
    k_gemm_64_32<<<(n + 31) / 32, TB, 0, stream>>>(bufB, W2, dinv, h2, n);
    k_agg32<<<(n + 3) / 4, TB, 0, stream>>>((const float4*)h2, off, eSrc, dinv,
                                            (const float4*)b2, (float4*)agg2, n);

    // ---- fc: out = agg2 @ Wfc + bfc ----
    k_fc2<<<(n + FC_ROWS - 1) / FC_ROWS, TB, 0, stream>>>(agg2, Wfc, bfc, out, n);
}